// Round 3
// baseline (518.298 us; speedup 1.0000x reference)
//
#include <hip/hip_runtime.h>

#define MDIM 8192
#define NDIM 4096
#define KDIM 4096
#define BM 256
#define BN 128
#define BK 128

typedef int v4i __attribute__((ext_vector_type(4)));
typedef int v16i __attribute__((ext_vector_type(16)));

__device__ __forceinline__ unsigned pack4(int x, int y, int z, int w) {
    return (unsigned)(x & 0xff) | ((unsigned)(y & 0xff) << 8) |
           ((unsigned)(z & 0xff) << 16) | ((unsigned)w << 24);
}

// ---- pass 1: int32 (int8-valued) -> packed int8, both tensors, one launch ----
__global__ __launch_bounds__(256) void pack_pair(const int* __restrict__ x,
                                                 const int* __restrict__ w,
                                                 uint4* __restrict__ xp,
                                                 uint4* __restrict__ wp) {
    const int i = blockIdx.x * 256 + threadIdx.x;  // one group of 16 ints
    const int xgroups = MDIM * KDIM / 16;          // block-uniform branch
    const int* src;
    uint4* dst;
    int g;
    if (i < xgroups) { src = x; dst = xp; g = i; }
    else             { src = w; dst = wp; g = i - xgroups; }
    const int4* p = (const int4*)src + (size_t)g * 4;
    int4 a = p[0], b = p[1], c = p[2], d = p[3];
    uint4 r;
    r.x = pack4(a.x, a.y, a.z, a.w);
    r.y = pack4(b.x, b.y, b.z, b.w);
    r.z = pack4(c.x, c.y, c.z, c.w);
    r.w = pack4(d.x, d.y, d.z, d.w);
    dst[g] = r;
}

// ---- pass 2: int8 GEMM, out = x @ W^T ----
// Block tile 256x128, BK=128. 256 threads = 4 waves (2x2); each wave 128x64
// via 4x2 mfma_i32_32x32x32_i8 over 4 ks-steps. LDS 48KB single-buffer,
// kb-major layout: A[kb 0..7][row 0..255][16B] @0, B[kb][row 0..127][16B]
// @32768. Every ds_read_b128 fragment read is two contiguous 512B half-wave
// segments (8 lanes x 16B = all 32 banks, 1 dword each) -> conflict-free;
// global_load_lds writes (lane*16 contiguous) likewise. The kb-major remap is
// done on the global source address, honoring the wave-uniform-dest rule.
template <bool PACKED>
__global__ __launch_bounds__(256, 2) void gemm_i8(const char* __restrict__ Ap,
                                                  const char* __restrict__ Bp,
                                                  const int* __restrict__ A32,
                                                  const int* __restrict__ B32,
                                                  const _Float16* __restrict__ bias,
                                                  _Float16* __restrict__ out) {
    __shared__ char lds[49152];

    const int tid  = threadIdx.x;
    const int lane = tid & 63;
    const int wave = tid >> 6;
    const int bm0 = blockIdx.y * BM;
    const int bn0 = blockIdx.x * BN;

    // staging: A = 32 chunks of 1024B (8/wave), B = 16 chunks (4/wave).
    // A chunk c: kb=c>>2, rows (c&3)*64 + lane. B chunk c: kb=c>>1, rows (c&1)*64 + lane.
    int aoffs[8], boffs[4];
    char* adst[8];
    char* bdst[4];
#pragma unroll
    for (int r = 0; r < 8; ++r) {
        const int c  = r * 4 + wave;
        const int kb = c >> 2;
        const int rowb = (c & 3) * 64;
        aoffs[r] = (bm0 + rowb + lane) * KDIM + kb * 16;
        adst[r]  = lds + c * 1024;
    }
#pragma unroll
    for (int r = 0; r < 4; ++r) {
        const int c  = r * 4 + wave;
        const int kb = c >> 1;
        const int rowb = (c & 1) * 64;
        boffs[r] = (bn0 + rowb + lane) * KDIM + kb * 16;
        bdst[r]  = lds + 32768 + c * 1024;
    }

    // fragment base addresses: af[mt][ks] @ abase[mt] + ks*8192 (kb=2ks+kg),
    // bf[nt][ks] @ bbase[nt] + ks*4096
    const int wr  = wave >> 1;
    const int wc  = wave & 1;
    const int l31 = lane & 31;
    const int kg  = lane >> 5;
    int abase[4], bbase[2];
#pragma unroll
    for (int mt = 0; mt < 4; ++mt)
        abase[mt] = kg * 4096 + (wr * 128 + mt * 32 + l31) * 16;
#pragma unroll
    for (int nt = 0; nt < 2; ++nt)
        bbase[nt] = 32768 + kg * 2048 + (wc * 64 + nt * 32 + l31) * 16;

    v16i acc[4][2];
#pragma unroll
    for (int mt = 0; mt < 4; ++mt)
#pragma unroll
        for (int nt = 0; nt < 2; ++nt)
#pragma unroll
            for (int i = 0; i < 16; ++i) acc[mt][nt][i] = 0;

    for (int k0 = 0; k0 < KDIM; k0 += BK) {
        if constexpr (PACKED) {
#pragma unroll
            for (int r = 0; r < 8; ++r) {
                __builtin_amdgcn_global_load_lds(
                    (__attribute__((address_space(1))) void*)(Ap + aoffs[r]),
                    (__attribute__((address_space(3))) void*)(adst[r]), 16, 0, 0);
                aoffs[r] += BK;
            }
#pragma unroll
            for (int r = 0; r < 4; ++r) {
                __builtin_amdgcn_global_load_lds(
                    (__attribute__((address_space(1))) void*)(Bp + boffs[r]),
                    (__attribute__((address_space(3))) void*)(bdst[r]), 16, 0, 0);
                boffs[r] += BK;
            }
        } else {
            // fallback: int32 loads, pack in regs, contiguous ds_write
#pragma unroll
            for (int r = 0; r < 8; ++r) {
                const int4* s = (const int4*)(A32 + (size_t)aoffs[r]);
                int4 v0 = s[0], v1 = s[1], v2 = s[2], v3 = s[3];
                uint4 pk;
                pk.x = pack4(v0.x, v0.y, v0.z, v0.w);
                pk.y = pack4(v1.x, v1.y, v1.z, v1.w);
                pk.z = pack4(v2.x, v2.y, v2.z, v2.w);
                pk.w = pack4(v3.x, v3.y, v3.z, v3.w);
                *(uint4*)(adst[r] + lane * 16) = pk;
                aoffs[r] += BK;
            }
#pragma unroll
            for (int r = 0; r < 4; ++r) {
                const int4* s = (const int4*)(B32 + (size_t)boffs[r]);
                int4 v0 = s[0], v1 = s[1], v2 = s[2], v3 = s[3];
                uint4 pk;
                pk.x = pack4(v0.x, v0.y, v0.z, v0.w);
                pk.y = pack4(v1.x, v1.y, v1.z, v1.w);
                pk.z = pack4(v2.x, v2.y, v2.z, v2.w);
                pk.w = pack4(v3.x, v3.y, v3.z, v3.w);
                *(uint4*)(bdst[r] + lane * 16) = pk;
                boffs[r] += BK;
            }
        }
        __syncthreads();

#pragma unroll
        for (int ks = 0; ks < 4; ++ks) {
            v4i af[4], bf[2];
#pragma unroll
            for (int mt = 0; mt < 4; ++mt)
                af[mt] = *(const v4i*)(lds + abase[mt] + ks * 8192);
#pragma unroll
            for (int nt = 0; nt < 2; ++nt)
                bf[nt] = *(const v4i*)(lds + bbase[nt] + ks * 4096);
#pragma unroll
            for (int mt = 0; mt < 4; ++mt)
#pragma unroll
                for (int nt = 0; nt < 2; ++nt)
                    acc[mt][nt] = __builtin_amdgcn_mfma_i32_32x32x32_i8(
                        af[mt], bf[nt], acc[mt][nt], 0, 0, 0);
        }

        __syncthreads();
    }

    // epilogue: int32 -> fp16 (exact: |v|<2^24 exact in f32; larger -> f16 inf
    // either way), + bias in fp16. C/D layout: col=lane&31,
    // row=(reg&3)+8*(reg>>2)+4*(lane>>5)
    const _Float16 bv0 = bias[bn0 + wc * 64 + l31];
    const _Float16 bv1 = bias[bn0 + wc * 64 + 32 + l31];
#pragma unroll
    for (int mt = 0; mt < 4; ++mt) {
#pragma unroll
        for (int nt = 0; nt < 2; ++nt) {
            const int gcol = bn0 + wc * 64 + nt * 32 + l31;
            const _Float16 bb = nt ? bv1 : bv0;
#pragma unroll
            for (int r = 0; r < 16; ++r) {
                const int rit  = (r & 3) + 8 * (r >> 2) + 4 * kg;
                const int grow = bm0 + wr * 128 + mt * 32 + rit;
                _Float16 h = (_Float16)(float)acc[mt][nt][r] + bb;
                out[(size_t)grow * NDIM + gcol] = h;
            }
        }
    }
}

extern "C" void kernel_launch(void* const* d_in, const int* in_sizes, int n_in,
                              void* d_out, int out_size, void* d_ws, size_t ws_size,
                              hipStream_t stream) {
    const int* x = (const int*)d_in[0];
    const int* w = (const int*)d_in[1];
    const _Float16* bias = (const _Float16*)d_in[2];
    _Float16* out = (_Float16*)d_out;

    const size_t xbytes = (size_t)MDIM * KDIM;  // packed int8 bytes
    const size_t wbytes = (size_t)NDIM * KDIM;

    if (ws_size >= xbytes + wbytes) {
        char* xp = (char*)d_ws;
        char* wp = xp + xbytes;
        pack_pair<<<(MDIM + NDIM) * KDIM / 16 / 256, 256, 0, stream>>>(
            x, w, (uint4*)xp, (uint4*)wp);
        gemm_i8<true><<<dim3(NDIM / BN, MDIM / BM), 256, 0, stream>>>(
            xp, wp, nullptr, nullptr, bias, out);
    } else {
        gemm_i8<false><<<dim3(NDIM / BN, MDIM / BM), 256, 0, stream>>>(
            nullptr, nullptr, x, w, bias, out);
    }
}

// Round 4
// 411.802 us; speedup vs baseline: 1.2586x; 1.2586x over previous
//
#include <hip/hip_runtime.h>

#define MDIM 8192
#define NDIM 4096
#define KDIM 4096
#define BM 256
#define BN 128
#define BK 128

typedef int v4i __attribute__((ext_vector_type(4)));
typedef int v16i __attribute__((ext_vector_type(16)));

__device__ __forceinline__ unsigned pack4(int x, int y, int z, int w) {
    return (unsigned)(x & 0xff) | ((unsigned)(y & 0xff) << 8) |
           ((unsigned)(z & 0xff) << 16) | ((unsigned)w << 24);
}

// ---- pass 1: int32 -> packed int8, PRE-TILED into GEMM staging order ----
// A layout: [mtile 0..31][kiter 0..31][kb 0..7][row 0..255] x 16B granules
// B layout: [ntile 0..31][kiter 0..31][kb 0..7][row 0..127] x 16B granules
// One workgroup per (tile, kiter) subtile; transpose via padded LDS (pitch 33
// dwords) so global reads AND writes are fully coalesced.
__global__ __launch_bounds__(256) void pack_tiled(const int* __restrict__ x,
                                                  const int* __restrict__ w,
                                                  uint4* __restrict__ xp,
                                                  uint4* __restrict__ wp) {
    __shared__ unsigned lds32[256 * 33];
    const int wg  = blockIdx.x;
    const int tid = threadIdx.x;
    const int kq   = tid & 31;   // which int4 (4 ints) within the 128-k window
    const int rsub = tid >> 5;   // row-within-iteration

    if (wg < 1024) {  // A / x subtiles: 256 rows x 128 k
        const int mtile = wg >> 5, kiter = wg & 31;
        const int* base = x + (size_t)(mtile * 256) * KDIM + kiter * 128;
#pragma unroll
        for (int it = 0; it < 32; ++it) {
            const int row = it * 8 + rsub;
            int4 v = *(const int4*)(base + (size_t)row * KDIM + kq * 4);
            lds32[row * 33 + kq] = pack4(v.x, v.y, v.z, v.w);
        }
        __syncthreads();
        uint4* dst = xp + (size_t)(mtile * 32 + kiter) * 8192;
#pragma unroll
        for (int it = 0; it < 8; ++it) {
            const int g = it * 256 + tid;
            const int kb = g >> 8, row = g & 255;
            const unsigned* p = &lds32[row * 33 + kb * 4];
            uint4 o;
            o.x = p[0]; o.y = p[1]; o.z = p[2]; o.w = p[3];
            dst[g] = o;
        }
    } else {  // B / w subtiles: 128 rows x 128 k
        const int ntile = (wg - 1024) >> 5, kiter = wg & 31;
        const int* base = w + (size_t)(ntile * 128) * KDIM + kiter * 128;
#pragma unroll
        for (int it = 0; it < 16; ++it) {
            const int row = it * 8 + rsub;
            int4 v = *(const int4*)(base + (size_t)row * KDIM + kq * 4);
            lds32[row * 33 + kq] = pack4(v.x, v.y, v.z, v.w);
        }
        __syncthreads();
        uint4* dst = wp + (size_t)(ntile * 32 + kiter) * 4096;
#pragma unroll
        for (int it = 0; it < 16; ++it) {
            const int g = it * 256 + tid;
            const int kb = g >> 7, row = g & 127;
            const unsigned* p = &lds32[row * 33 + kb * 4];
            uint4 o;
            o.x = p[0]; o.y = p[1]; o.z = p[2]; o.w = p[3];
            dst[g] = o;
        }
    }
}

// ---- pass 2: int8 GEMM, out = x @ W^T ----
// Block tile 256x128, BK=128. 256 threads = 4 waves (2x2); each wave 128x64
// via 4x2 mfma_i32_32x32x32_i8 over 4 ks-steps. LDS 48KB single-buffer,
// kb-major: A[kb][row][16B] @0, B[kb][row][16B] @32768. Fragment ds_read_b128
// = contiguous 512B half-wave segments -> conflict-free. Staging reads the
// PRE-TILED packed arrays fully sequentially (1024B contiguous per chunk).
template <bool PACKED>
__global__ __launch_bounds__(256, 2) void gemm_i8(const char* __restrict__ Ap,
                                                  const char* __restrict__ Bp,
                                                  const int* __restrict__ A32,
                                                  const int* __restrict__ B32,
                                                  const _Float16* __restrict__ bias,
                                                  _Float16* __restrict__ out) {
    __shared__ char lds[49152];

    const int tid  = threadIdx.x;
    const int lane = tid & 63;
    const int wave = tid >> 6;
    const int bm0 = blockIdx.y * BM;
    const int bn0 = blockIdx.x * BN;

    // pre-tiled panel cursors (PACKED path): contiguous sequential scan
    const char* apan = Ap + (size_t)blockIdx.y * (BM * KDIM) + lane * 16;
    const char* bpan = Bp + (size_t)blockIdx.x * (BN * KDIM) + lane * 16;

    // fallback cursors (kb-major gather from row-major int32)
    int aoffs[8], boffs[4];
    if constexpr (!PACKED) {
#pragma unroll
        for (int r = 0; r < 8; ++r) {
            const int c = r * 4 + wave;
            aoffs[r] = (bm0 + (c & 3) * 64 + lane) * KDIM + (c >> 2) * 16;
        }
#pragma unroll
        for (int r = 0; r < 4; ++r) {
            const int c = r * 4 + wave;
            boffs[r] = (bn0 + (c & 1) * 64 + lane) * KDIM + (c >> 1) * 16;
        }
    }

    // fragment base addresses: af[mt][ks] @ abase[mt] + ks*8192 (kb=2ks+kg),
    // bf[nt][ks] @ bbase[nt] + ks*4096
    const int wr  = wave >> 1;
    const int wc  = wave & 1;
    const int l31 = lane & 31;
    const int kg  = lane >> 5;
    int abase[4], bbase[2];
#pragma unroll
    for (int mt = 0; mt < 4; ++mt)
        abase[mt] = kg * 4096 + (wr * 128 + mt * 32 + l31) * 16;
#pragma unroll
    for (int nt = 0; nt < 2; ++nt)
        bbase[nt] = 32768 + kg * 2048 + (wc * 64 + nt * 32 + l31) * 16;

    v16i acc[4][2];
#pragma unroll
    for (int mt = 0; mt < 4; ++mt)
#pragma unroll
        for (int nt = 0; nt < 2; ++nt)
#pragma unroll
            for (int i = 0; i < 16; ++i) acc[mt][nt][i] = 0;

    for (int k0 = 0; k0 < KDIM; k0 += BK) {
        if constexpr (PACKED) {
#pragma unroll
            for (int r = 0; r < 8; ++r) {
                const int c = r * 4 + wave;
                __builtin_amdgcn_global_load_lds(
                    (__attribute__((address_space(1))) void*)(apan + c * 1024),
                    (__attribute__((address_space(3))) void*)(lds + c * 1024), 16, 0, 0);
            }
#pragma unroll
            for (int r = 0; r < 4; ++r) {
                const int c = r * 4 + wave;
                __builtin_amdgcn_global_load_lds(
                    (__attribute__((address_space(1))) void*)(bpan + c * 1024),
                    (__attribute__((address_space(3))) void*)(lds + 32768 + c * 1024), 16, 0, 0);
            }
            apan += BM * BK;  // 32768
            bpan += BN * BK;  // 16384
        } else {
#pragma unroll
            for (int r = 0; r < 8; ++r) {
                const int c = r * 4 + wave;
                const int4* s = (const int4*)(A32 + (size_t)aoffs[r]);
                int4 v0 = s[0], v1 = s[1], v2 = s[2], v3 = s[3];
                uint4 pk;
                pk.x = pack4(v0.x, v0.y, v0.z, v0.w);
                pk.y = pack4(v1.x, v1.y, v1.z, v1.w);
                pk.z = pack4(v2.x, v2.y, v2.z, v2.w);
                pk.w = pack4(v3.x, v3.y, v3.z, v3.w);
                *(uint4*)(lds + c * 1024 + lane * 16) = pk;
                aoffs[r] += BK;
            }
#pragma unroll
            for (int r = 0; r < 4; ++r) {
                const int c = r * 4 + wave;
                const int4* s = (const int4*)(B32 + (size_t)boffs[r]);
                int4 v0 = s[0], v1 = s[1], v2 = s[2], v3 = s[3];
                uint4 pk;
                pk.x = pack4(v0.x, v0.y, v0.z, v0.w);
                pk.y = pack4(v1.x, v1.y, v1.z, v1.w);
                pk.z = pack4(v2.x, v2.y, v2.z, v2.w);
                pk.w = pack4(v3.x, v3.y, v3.z, v3.w);
                *(uint4*)(lds + 32768 + c * 1024 + lane * 16) = pk;
                boffs[r] += BK;
            }
        }
        __syncthreads();

#pragma unroll
        for (int ks = 0; ks < 4; ++ks) {
            v4i af[4], bf[2];
#pragma unroll
            for (int mt = 0; mt < 4; ++mt)
                af[mt] = *(const v4i*)(lds + abase[mt] + ks * 8192);
#pragma unroll
            for (int nt = 0; nt < 2; ++nt)
                bf[nt] = *(const v4i*)(lds + bbase[nt] + ks * 4096);
#pragma unroll
            for (int mt = 0; mt < 4; ++mt)
#pragma unroll
                for (int nt = 0; nt < 2; ++nt)
                    acc[mt][nt] = __builtin_amdgcn_mfma_i32_32x32x32_i8(
                        af[mt], bf[nt], acc[mt][nt], 0, 0, 0);
        }

        __syncthreads();
    }

    // epilogue: int32 -> fp16 (exact; overflow -> inf matches ref), + bias.
    // C/D layout: col=lane&31, row=(reg&3)+8*(reg>>2)+4*(lane>>5)
    const _Float16 bv0 = bias[bn0 + wc * 64 + l31];
    const _Float16 bv1 = bias[bn0 + wc * 64 + 32 + l31];
#pragma unroll
    for (int mt = 0; mt < 4; ++mt) {
#pragma unroll
        for (int nt = 0; nt < 2; ++nt) {
            const int gcol = bn0 + wc * 64 + nt * 32 + l31;
            const _Float16 bb = nt ? bv1 : bv0;
#pragma unroll
            for (int r = 0; r < 16; ++r) {
                const int rit  = (r & 3) + 8 * (r >> 2) + 4 * kg;
                const int grow = bm0 + wr * 128 + mt * 32 + rit;
                _Float16 h = (_Float16)(float)acc[mt][nt][r] + bb;
                out[(size_t)grow * NDIM + gcol] = h;
            }
        }
    }
}

extern "C" void kernel_launch(void* const* d_in, const int* in_sizes, int n_in,
                              void* d_out, int out_size, void* d_ws, size_t ws_size,
                              hipStream_t stream) {
    const int* x = (const int*)d_in[0];
    const int* w = (const int*)d_in[1];
    const _Float16* bias = (const _Float16*)d_in[2];
    _Float16* out = (_Float16*)d_out;

    const size_t xbytes = (size_t)MDIM * KDIM;  // packed int8 bytes
    const size_t wbytes = (size_t)NDIM * KDIM;

    if (ws_size >= xbytes + wbytes) {
        char* xp = (char*)d_ws;
        char* wp = xp + xbytes;
        pack_tiled<<<2048, 256, 0, stream>>>(x, w, (uint4*)xp, (uint4*)wp);
        gemm_i8<true><<<dim3(NDIM / BN, MDIM / BM), 256, 0, stream>>>(
            xp, wp, nullptr, nullptr, bias, out);
    } else {
        gemm_i8<false><<<dim3(NDIM / BN, MDIM / BM), 256, 0, stream>>>(
            nullptr, nullptr, x, w, bias, out);
    }
}

// Round 5
// 396.837 us; speedup vs baseline: 1.3061x; 1.0377x over previous
//
#include <hip/hip_runtime.h>

#define MDIM 8192
#define NDIM 4096
#define KDIM 4096
#define BM 256
#define BN 128
#define BK 128

typedef int v4i __attribute__((ext_vector_type(4)));
typedef int v16i __attribute__((ext_vector_type(16)));

__device__ __forceinline__ unsigned pack4(int x, int y, int z, int w) {
    return (unsigned)(x & 0xff) | ((unsigned)(y & 0xff) << 8) |
           ((unsigned)(z & 0xff) << 16) | ((unsigned)w << 24);
}

// ---- pass 1: int32 -> packed int8, pre-tiled ----
// A: [mtile][kiter][kb 0..7][row 0..255] 16B granules; subtile = 2048 granules
//    (granule g: kb=g>>8, row=g&255, bytes k = kb*16..+15 of the 128-k window)
// B: [ntile][kiter][h 0..15][lane 0..63] 16B granules; subtile = 1024 granules
//    h = wc*8 + nt*4 + ks; lane holds B[row=wc*64+nt*32+(lane&31)]
//    [k=(2ks+(lane>>5))*16 ..+15]  == exact MFMA B-fragment order per wave.
// Transpose via padded LDS (pitch 33 dwords); global reads and writes coalesced.
__global__ __launch_bounds__(256) void pack_tiled(const int* __restrict__ x,
                                                  const int* __restrict__ w,
                                                  uint4* __restrict__ xp,
                                                  uint4* __restrict__ wp) {
    __shared__ unsigned lds32[256 * 33];
    const int wg  = blockIdx.x;
    const int tid = threadIdx.x;
    const int kq   = tid & 31;   // which packed dword (4 ints) in 128-k window
    const int rsub = tid >> 5;

    if (wg < 1024) {  // A subtiles: 256 rows x 128 k
        const int mtile = wg >> 5, kiter = wg & 31;
        const int* base = x + (size_t)(mtile * 256) * KDIM + kiter * 128;
#pragma unroll
        for (int it = 0; it < 32; ++it) {
            const int row = it * 8 + rsub;
            int4 v = *(const int4*)(base + (size_t)row * KDIM + kq * 4);
            lds32[row * 33 + kq] = pack4(v.x, v.y, v.z, v.w);
        }
        __syncthreads();
        uint4* dst = xp + (size_t)(mtile * 32 + kiter) * 2048;
#pragma unroll
        for (int it = 0; it < 8; ++it) {
            const int g = it * 256 + tid;           // 0..2047
            const int kb = g >> 8, row = g & 255;   // kb 0..7
            const unsigned* p = &lds32[row * 33 + kb * 4];
            uint4 o;
            o.x = p[0]; o.y = p[1]; o.z = p[2]; o.w = p[3];
            dst[g] = o;
        }
    } else {  // B subtiles: 128 rows x 128 k
        const int ntile = (wg - 1024) >> 5, kiter = wg & 31;
        const int* base = w + (size_t)(ntile * 128) * KDIM + kiter * 128;
#pragma unroll
        for (int it = 0; it < 16; ++it) {
            const int row = it * 8 + rsub;
            int4 v = *(const int4*)(base + (size_t)row * KDIM + kq * 4);
            lds32[row * 33 + kq] = pack4(v.x, v.y, v.z, v.w);
        }
        __syncthreads();
        uint4* dst = wp + (size_t)(ntile * 32 + kiter) * 1024;
#pragma unroll
        for (int it = 0; it < 4; ++it) {
            const int g  = it * 256 + tid;          // 0..1023
            const int ln = g & 63, h = g >> 6;      // h 0..15
            const int wc2 = h >> 3, nt = (h >> 2) & 1, ks = h & 3;
            const int row = wc2 * 64 + nt * 32 + (ln & 31);
            const int kb  = 2 * ks + (ln >> 5);     // 0..7
            const unsigned* p = &lds32[row * 33 + kb * 4];
            uint4 o;
            o.x = p[0]; o.y = p[1]; o.z = p[2]; o.w = p[3];
            dst[g] = o;
        }
    }
}

// ---- pass 2: int8 GEMM, out = x @ W^T ----
// Block 256x128, BK=128, 4 waves (2x2), wave = 128x64 via 4x2
// mfma_i32_32x32x32_i8 over 4 ks. A staged to 32KB LDS (kb-major, conflict-free
// b128 reads: contiguous 512B half-wave segments). B fragments loaded DIRECTLY
// to VGPRs from the fragment-ordered packed array (coalesced 1KB loads,
// L2/L3-resident) -- no LDS traffic for B at all.
template <bool PACKED>
__global__ __launch_bounds__(256, 2) void gemm_i8(const char* __restrict__ Ap,
                                                  const char* __restrict__ Bp,
                                                  const int* __restrict__ A32,
                                                  const int* __restrict__ B32,
                                                  const _Float16* __restrict__ bias,
                                                  _Float16* __restrict__ out) {
    __shared__ char lds[32768];  // A only: [kb 0..7][row 0..255] x 16B

    const int tid  = threadIdx.x;
    const int lane = tid & 63;
    const int wave = tid >> 6;
    const int bm0 = blockIdx.y * BM;
    const int bn0 = blockIdx.x * BN;
    const int wr  = wave >> 1;
    const int wc  = wave & 1;
    const int l31 = lane & 31;
    const int kg  = lane >> 5;

    // A panel cursor: contiguous scan; chunk c at +c*1024, +32768 per kit.
    const char* apan = Ap + (size_t)blockIdx.y * (BM * KDIM) + lane * 16;
    // B panel cursor: wave's 8 fragment chunks at +(nt*4+ks)*1024, +16384 per kit.
    const char* bpan = Bp + (size_t)blockIdx.x * (BN * KDIM) + wc * 8192 + lane * 16;

    // fallback cursors
    int aoffs[8];
    if constexpr (!PACKED) {
#pragma unroll
        for (int r = 0; r < 8; ++r) {
            const int c = r * 4 + wave;
            aoffs[r] = (bm0 + (c & 3) * 64 + lane) * KDIM + (c >> 2) * 16;
        }
    }

    // A fragment bases: af[mt] @ abase[mt] + ks*8192 (kb = 2ks+kg)
    int abase[4];
#pragma unroll
    for (int mt = 0; mt < 4; ++mt)
        abase[mt] = kg * 4096 + (wr * 128 + mt * 32 + l31) * 16;

    v16i acc[4][2];
#pragma unroll
    for (int mt = 0; mt < 4; ++mt)
#pragma unroll
        for (int nt = 0; nt < 2; ++nt)
#pragma unroll
            for (int i = 0; i < 16; ++i) acc[mt][nt][i] = 0;

    for (int k0 = 0; k0 < KDIM; k0 += BK) {
        v4i bf[2][4];
        if constexpr (PACKED) {
#pragma unroll
            for (int r = 0; r < 8; ++r) {
                const int c = r * 4 + wave;
                __builtin_amdgcn_global_load_lds(
                    (__attribute__((address_space(1))) void*)(apan + c * 1024),
                    (__attribute__((address_space(3))) void*)(lds + c * 1024), 16, 0, 0);
            }
#pragma unroll
            for (int nt = 0; nt < 2; ++nt)
#pragma unroll
                for (int ks = 0; ks < 4; ++ks)
                    bf[nt][ks] = *(const v4i*)(bpan + (nt * 4 + ks) * 1024);
            apan += BM * BK;  // 32768
            bpan += BN * BK;  // 16384
        } else {
#pragma unroll
            for (int r = 0; r < 8; ++r) {
                const int c = r * 4 + wave;
                const int4* s = (const int4*)(A32 + (size_t)aoffs[r]);
                int4 v0 = s[0], v1 = s[1], v2 = s[2], v3 = s[3];
                uint4 pk;
                pk.x = pack4(v0.x, v0.y, v0.z, v0.w);
                pk.y = pack4(v1.x, v1.y, v1.z, v1.w);
                pk.z = pack4(v2.x, v2.y, v2.z, v2.w);
                pk.w = pack4(v3.x, v3.y, v3.z, v3.w);
                *(uint4*)(lds + c * 1024 + lane * 16) = pk;
                aoffs[r] += BK;
            }
#pragma unroll
            for (int nt = 0; nt < 2; ++nt)
#pragma unroll
                for (int ks = 0; ks < 4; ++ks) {
                    const int* s = B32 + (size_t)(bn0 + wc * 64 + nt * 32 + l31) * KDIM
                                   + k0 + (2 * ks + kg) * 16;
                    int4 v0 = ((const int4*)s)[0], v1 = ((const int4*)s)[1];
                    int4 v2 = ((const int4*)s)[2], v3 = ((const int4*)s)[3];
                    bf[nt][ks][0] = (int)pack4(v0.x, v0.y, v0.z, v0.w);
                    bf[nt][ks][1] = (int)pack4(v1.x, v1.y, v1.z, v1.w);
                    bf[nt][ks][2] = (int)pack4(v2.x, v2.y, v2.z, v2.w);
                    bf[nt][ks][3] = (int)pack4(v3.x, v3.y, v3.z, v3.w);
                }
        }
        __syncthreads();  // drains A DMA (and B loads) before fragment reads

#pragma unroll
        for (int ks = 0; ks < 4; ++ks) {
            v4i af[4];
#pragma unroll
            for (int mt = 0; mt < 4; ++mt)
                af[mt] = *(const v4i*)(lds + abase[mt] + ks * 8192);
#pragma unroll
            for (int mt = 0; mt < 4; ++mt)
#pragma unroll
                for (int nt = 0; nt < 2; ++nt)
                    acc[mt][nt] = __builtin_amdgcn_mfma_i32_32x32x32_i8(
                        af[mt], bf[nt][ks], acc[mt][nt], 0, 0, 0);
        }

        __syncthreads();
    }

    // epilogue: int32 -> fp16 (exact; overflow -> inf matches ref), + bias.
    // C/D layout: col=lane&31, row=(reg&3)+8*(reg>>2)+4*(lane>>5)
    const _Float16 bv0 = bias[bn0 + wc * 64 + l31];
    const _Float16 bv1 = bias[bn0 + wc * 64 + 32 + l31];
#pragma unroll
    for (int mt = 0; mt < 4; ++mt) {
#pragma unroll
        for (int nt = 0; nt < 2; ++nt) {
            const int gcol = bn0 + wc * 64 + nt * 32 + l31;
            const _Float16 bb = nt ? bv1 : bv0;
#pragma unroll
            for (int r = 0; r < 16; ++r) {
                const int rit  = (r & 3) + 8 * (r >> 2) + 4 * kg;
                const int grow = bm0 + wr * 128 + mt * 32 + rit;
                _Float16 h = (_Float16)(float)acc[mt][nt][r] + bb;
                out[(size_t)grow * NDIM + gcol] = h;
            }
        }
    }
}

extern "C" void kernel_launch(void* const* d_in, const int* in_sizes, int n_in,
                              void* d_out, int out_size, void* d_ws, size_t ws_size,
                              hipStream_t stream) {
    const int* x = (const int*)d_in[0];
    const int* w = (const int*)d_in[1];
    const _Float16* bias = (const _Float16*)d_in[2];
    _Float16* out = (_Float16*)d_out;

    const size_t xbytes = (size_t)MDIM * KDIM;  // packed int8 bytes
    const size_t wbytes = (size_t)NDIM * KDIM;

    if (ws_size >= xbytes + wbytes) {
        char* xp = (char*)d_ws;
        char* wp = xp + xbytes;
        pack_tiled<<<2048, 256, 0, stream>>>(x, w, (uint4*)xp, (uint4*)wp);
        gemm_i8<true><<<dim3(NDIM / BN, MDIM / BM), 256, 0, stream>>>(
            xp, wp, nullptr, nullptr, bias, out);
    } else {
        gemm_i8<false><<<dim3(NDIM / BN, MDIM / BM), 256, 0, stream>>>(
            nullptr, nullptr, x, w, bias, out);
    }
}

// Round 6
// 386.754 us; speedup vs baseline: 1.3401x; 1.0261x over previous
//
#include <hip/hip_runtime.h>

#define MDIM 8192
#define NDIM 4096
#define KDIM 4096
#define BM 256
#define BN 128
#define BK 128

typedef int v4i __attribute__((ext_vector_type(4)));
typedef int v16i __attribute__((ext_vector_type(16)));

__device__ __forceinline__ unsigned pack4(int x, int y, int z, int w) {
    return (unsigned)(x & 0xff) | ((unsigned)(y & 0xff) << 8) |
           ((unsigned)(z & 0xff) << 16) | ((unsigned)w << 24);
}

// ---- pass 1: int32 -> packed int8, pre-tiled ----
// A: [mtile][kiter][kb 0..7][row 0..255] 16B granules; subtile = 2048 granules
// B: [ntile][kiter][h 0..15][lane 0..63] 16B granules; subtile = 1024 granules
//    h = wc*8 + nt*4 + ks; lane holds B[row=wc*64+nt*32+(lane&31)]
//    [k=(2ks+(lane>>5))*16 ..+15]  == exact MFMA B-fragment order per wave.
// Transpose via padded LDS (pitch 33 dwords); global reads and writes coalesced.
__global__ __launch_bounds__(256) void pack_tiled(const int* __restrict__ x,
                                                  const int* __restrict__ w,
                                                  uint4* __restrict__ xp,
                                                  uint4* __restrict__ wp) {
    __shared__ unsigned lds32[256 * 33];
    const int wg  = blockIdx.x;
    const int tid = threadIdx.x;
    const int kq   = tid & 31;
    const int rsub = tid >> 5;

    if (wg < 1024) {  // A subtiles: 256 rows x 128 k
        const int mtile = wg >> 5, kiter = wg & 31;
        const int* base = x + (size_t)(mtile * 256) * KDIM + kiter * 128;
#pragma unroll
        for (int it = 0; it < 32; ++it) {
            const int row = it * 8 + rsub;
            int4 v = *(const int4*)(base + (size_t)row * KDIM + kq * 4);
            lds32[row * 33 + kq] = pack4(v.x, v.y, v.z, v.w);
        }
        __syncthreads();
        uint4* dst = xp + (size_t)(mtile * 32 + kiter) * 2048;
#pragma unroll
        for (int it = 0; it < 8; ++it) {
            const int g = it * 256 + tid;
            const int kb = g >> 8, row = g & 255;
            const unsigned* p = &lds32[row * 33 + kb * 4];
            uint4 o;
            o.x = p[0]; o.y = p[1]; o.z = p[2]; o.w = p[3];
            dst[g] = o;
        }
    } else {  // B subtiles: 128 rows x 128 k
        const int ntile = (wg - 1024) >> 5, kiter = wg & 31;
        const int* base = w + (size_t)(ntile * 128) * KDIM + kiter * 128;
#pragma unroll
        for (int it = 0; it < 16; ++it) {
            const int row = it * 8 + rsub;
            int4 v = *(const int4*)(base + (size_t)row * KDIM + kq * 4);
            lds32[row * 33 + kq] = pack4(v.x, v.y, v.z, v.w);
        }
        __syncthreads();
        uint4* dst = wp + (size_t)(ntile * 32 + kiter) * 1024;
#pragma unroll
        for (int it = 0; it < 4; ++it) {
            const int g  = it * 256 + tid;
            const int ln = g & 63, h = g >> 6;
            const int wc2 = h >> 3, nt = (h >> 2) & 1, ks = h & 3;
            const int row = wc2 * 64 + nt * 32 + (ln & 31);
            const int kb  = 2 * ks + (ln >> 5);
            const unsigned* p = &lds32[row * 33 + kb * 4];
            uint4 o;
            o.x = p[0]; o.y = p[1]; o.z = p[2]; o.w = p[3];
            dst[g] = o;
        }
    }
}

// ---- pass 2: int8 GEMM, out = x @ W^T ----
// Block 256x128, BK=128, 4 waves (2x2), wave = 128x64 via 4x2
// mfma_i32_32x32x32_i8 over 4 ks. PIPELINED 1-barrier K-loop:
//   barrier; issue A(k+1) DMA -> other LDS buf + B(k+1) loads -> other reg set;
//   compute(k). The compiler's vmcnt(0)-before-barrier then drains loads that
//   were issued a full compute phase earlier (latency hidden), instead of
//   loads issued immediately before the barrier (R5's 2-barrier stall).
// A double-buffered in LDS (2x32KB, kb-major, conflict-free b128 reads);
// B fragments double-buffered in VGPRs (fragment-ordered packed array).
template <bool PACKED>
__global__ __launch_bounds__(256, 2) void gemm_i8(const char* __restrict__ Ap,
                                                  const char* __restrict__ Bp,
                                                  const int* __restrict__ A32,
                                                  const int* __restrict__ B32,
                                                  const _Float16* __restrict__ bias,
                                                  _Float16* __restrict__ out) {
    __shared__ char lds[65536];

    const int tid  = threadIdx.x;
    const int lane = tid & 63;
    const int wave = tid >> 6;
    const int bm0 = blockIdx.y * BM;
    const int bn0 = blockIdx.x * BN;
    const int wr  = wave >> 1;
    const int wc  = wave & 1;
    const int l31 = lane & 31;
    const int kg  = lane >> 5;

    const char* apan = Ap + (size_t)blockIdx.y * (BM * KDIM) + lane * 16;
    const char* bpan = Bp + (size_t)blockIdx.x * (BN * KDIM) + wc * 8192 + lane * 16;

    int abase[4];
#pragma unroll
    for (int mt = 0; mt < 4; ++mt)
        abase[mt] = kg * 4096 + (wr * 128 + mt * 32 + l31) * 16;

    v16i acc[4][2];
#pragma unroll
    for (int mt = 0; mt < 4; ++mt)
#pragma unroll
        for (int nt = 0; nt < 2; ++nt)
#pragma unroll
            for (int i = 0; i < 16; ++i) acc[mt][nt][i] = 0;

    auto issueA = [&](char* buf, const char* pan) {
#pragma unroll
        for (int r = 0; r < 8; ++r) {
            const int c = r * 4 + wave;
            __builtin_amdgcn_global_load_lds(
                (__attribute__((address_space(1))) void*)(pan + c * 1024),
                (__attribute__((address_space(3))) void*)(buf + c * 1024), 16, 0, 0);
        }
    };
    auto loadB = [&](v4i (&bf)[2][4], const char* pan) {
#pragma unroll
        for (int nt = 0; nt < 2; ++nt)
#pragma unroll
            for (int ks = 0; ks < 4; ++ks)
                bf[nt][ks] = *(const v4i*)(pan + (nt * 4 + ks) * 1024);
    };
    auto compute = [&](const char* buf, const v4i (&bf)[2][4]) {
#pragma unroll
        for (int ks = 0; ks < 4; ++ks) {
            v4i af[4];
#pragma unroll
            for (int mt = 0; mt < 4; ++mt)
                af[mt] = *(const v4i*)(buf + abase[mt] + ks * 8192);
#pragma unroll
            for (int mt = 0; mt < 4; ++mt)
#pragma unroll
                for (int nt = 0; nt < 2; ++nt)
                    acc[mt][nt] = __builtin_amdgcn_mfma_i32_32x32x32_i8(
                        af[mt], bf[nt][ks], acc[mt][nt], 0, 0, 0);
        }
    };

    if constexpr (PACKED) {
        v4i bf0[2][4], bf1[2][4];
        // prologue: stage iter 0
        issueA(lds, apan);
        apan += BM * BK;
        loadB(bf0, bpan);
        bpan += BN * BK;
#pragma unroll 1
        for (int p = 0; p < 15; ++p) {  // iters 2p (buf0) and 2p+1 (buf1)
            __syncthreads();            // drains A(2p) DMA (issued last stage)
            issueA(lds + 32768, apan);  // prefetch iter 2p+1
            apan += BM * BK;
            loadB(bf1, bpan);
            bpan += BN * BK;
            compute(lds, bf0);          // iter 2p
            __syncthreads();
            issueA(lds, apan);          // prefetch iter 2p+2
            apan += BM * BK;
            loadB(bf0, bpan);
            bpan += BN * BK;
            compute(lds + 32768, bf1);  // iter 2p+1
        }
        __syncthreads();
        issueA(lds + 32768, apan);      // prefetch iter 31
        loadB(bf1, bpan);
        compute(lds, bf0);              // iter 30
        __syncthreads();
        compute(lds + 32768, bf1);      // iter 31
    } else {
        // fallback: non-pipelined, pack in regs from int32 (correctness path)
        int aoffs[8];
#pragma unroll
        for (int r = 0; r < 8; ++r) {
            const int c = r * 4 + wave;
            aoffs[r] = (bm0 + (c & 3) * 64 + lane) * KDIM + (c >> 2) * 16;
        }
        for (int k0 = 0; k0 < KDIM; k0 += BK) {
            v4i bfx[2][4];
#pragma unroll
            for (int r = 0; r < 8; ++r) {
                const int c = r * 4 + wave;
                const int4* s = (const int4*)(A32 + (size_t)aoffs[r]);
                int4 v0 = s[0], v1 = s[1], v2 = s[2], v3 = s[3];
                uint4 pk;
                pk.x = pack4(v0.x, v0.y, v0.z, v0.w);
                pk.y = pack4(v1.x, v1.y, v1.z, v1.w);
                pk.z = pack4(v2.x, v2.y, v2.z, v2.w);
                pk.w = pack4(v3.x, v3.y, v3.z, v3.w);
                *(uint4*)(lds + c * 1024 + lane * 16) = pk;
                aoffs[r] += BK;
            }
#pragma unroll
            for (int nt = 0; nt < 2; ++nt)
#pragma unroll
                for (int ks = 0; ks < 4; ++ks) {
                    const int* s = B32 + (size_t)(bn0 + wc * 64 + nt * 32 + l31) * KDIM
                                   + k0 + (2 * ks + kg) * 16;
                    int4 v0 = ((const int4*)s)[0], v1 = ((const int4*)s)[1];
                    int4 v2 = ((const int4*)s)[2], v3 = ((const int4*)s)[3];
                    bfx[nt][ks][0] = (int)pack4(v0.x, v0.y, v0.z, v0.w);
                    bfx[nt][ks][1] = (int)pack4(v1.x, v1.y, v1.z, v1.w);
                    bfx[nt][ks][2] = (int)pack4(v2.x, v2.y, v2.z, v2.w);
                    bfx[nt][ks][3] = (int)pack4(v3.x, v3.y, v3.z, v3.w);
                }
            __syncthreads();
            compute(lds, bfx);
            __syncthreads();
        }
    }

    // epilogue: int32 -> fp16 (exact; overflow -> inf matches ref), + bias.
    // C/D layout: col=lane&31, row=(reg&3)+8*(reg>>2)+4*(lane>>5)
    const _Float16 bv0 = bias[bn0 + wc * 64 + l31];
    const _Float16 bv1 = bias[bn0 + wc * 64 + 32 + l31];
#pragma unroll
    for (int mt = 0; mt < 4; ++mt) {
#pragma unroll
        for (int nt = 0; nt < 2; ++nt) {
            const int gcol = bn0 + wc * 64 + nt * 32 + l31;
            const _Float16 bb = nt ? bv1 : bv0;
#pragma unroll
            for (int r = 0; r < 16; ++r) {
                const int rit  = (r & 3) + 8 * (r >> 2) + 4 * kg;
                const int grow = bm0 + wr * 128 + mt * 32 + rit;
                _Float16 h = (_Float16)(float)acc[mt][nt][r] + bb;
                out[(size_t)grow * NDIM + gcol] = h;
            }
        }
    }
}

extern "C" void kernel_launch(void* const* d_in, const int* in_sizes, int n_in,
                              void* d_out, int out_size, void* d_ws, size_t ws_size,
                              hipStream_t stream) {
    const int* x = (const int*)d_in[0];
    const int* w = (const int*)d_in[1];
    const _Float16* bias = (const _Float16*)d_in[2];
    _Float16* out = (_Float16*)d_out;

    const size_t xbytes = (size_t)MDIM * KDIM;  // packed int8 bytes
    const size_t wbytes = (size_t)NDIM * KDIM;

    if (ws_size >= xbytes + wbytes) {
        char* xp = (char*)d_ws;
        char* wp = xp + xbytes;
        pack_tiled<<<2048, 256, 0, stream>>>(x, w, (uint4*)xp, (uint4*)wp);
        gemm_i8<true><<<dim3(NDIM / BN, MDIM / BM), 256, 0, stream>>>(
            xp, wp, nullptr, nullptr, bias, out);
    } else {
        gemm_i8<false><<<dim3(NDIM / BN, MDIM / BM), 256, 0, stream>>>(
            nullptr, nullptr, x, w, bias, out);
    }
}